// Round 1
// baseline (110.957 us; speedup 1.0000x reference)
//
#include <hip/hip_runtime.h>
#include <hip/hip_bf16.h>

typedef __attribute__((ext_vector_type(8))) short short8;
typedef __attribute__((ext_vector_type(4))) float f32x4;

namespace {
constexpr int Nc  = 2048;   // N
constexpr int NXc = 4096;   // 2N
constexpr int Pc  = 64;
constexpr int Mc  = 4;
constexpr int Dc  = 256;
constexpr int BH  = 16;
constexpr int NCHUNK = 128;          // n-rows per block
constexpr int NT = NCHUNK / 16;      // 8 n-tiles per block
constexpr float LOG2E = 1.4426950408889634f;
}

__device__ inline float fexp2(float x) {
#if __has_builtin(__builtin_amdgcn_exp2f)
  return __builtin_amdgcn_exp2f(x);
#else
  return exp2f(x);
#endif
}

__device__ inline unsigned int bfpack(float a, float b) {
  union { __hip_bfloat162 h; unsigned int u; } cv;
  cv.h = __float22bfloat162_rn(make_float2(a, b));
  return cv.u;
}

// Gather-only pre-pass: Wb[bh][m*256+d][64] = bf16( LOG2E * X[bh][SK[b,m,d]][:] )
__global__ __launch_bounds__(256) void prepass_kernel(
    const float* __restrict__ Q, const float* __restrict__ K,
    const int* __restrict__ SK, __hip_bfloat16* __restrict__ Wb)
{
  const int t  = blockIdx.x * 256 + threadIdx.x;
  const int q  = t & 7;
  const int r  = t >> 3;            // 0..16383
  const int bh = r >> 10;
  const int md = r & 1023;
  const int b  = bh >> 3;
  const int idx = SK[b * (Mc * Dc) + md];
  const float* src = (idx < Nc) ? (Q + ((size_t)bh * Nc + idx) * Pc)
                                : (K + ((size_t)bh * Nc + (idx - Nc)) * Pc);
  const f32x4* s4 = (const f32x4*)(src + q * 8);
  f32x4 f0 = s4[0], f1 = s4[1];
  uint4 u;
  u.x = bfpack(f0.x * LOG2E, f0.y * LOG2E);
  u.y = bfpack(f0.z * LOG2E, f0.w * LOG2E);
  u.z = bfpack(f1.x * LOG2E, f1.y * LOG2E);
  u.w = bfpack(f1.z * LOG2E, f1.w * LOG2E);
  *(uint4*)(Wb + (size_t)r * Pc + q * 8) = u;
}

// Main kernel, restructured: W register-resident per wave, NO LDS, NO barriers.
//
// Each wave owns d-slice [wv*64, wv*64+64) for ALL m: its A-fragments
// (4 m x 4 dt x 2 k-halves = 32 short8 = 128 VGPRs) are loaded ONCE from L2,
// then reused across 8 n-tiles. Signs live in 64 VGPRs. X tiles are
// double-buffered in registers (16 f32/lane). Zero __syncthreads in the
// whole kernel; grid 512 blocks x 4 waves = 2048 waves = exactly 2/SIMD,
// fully co-resident.
//
// MFMA: A = W rows (d), B = X rows (n) => C: row = d (q*4+reg), col = n (brow).
__global__ __launch_bounds__(256, 2) void sketch_main(
    const float* __restrict__ Q, const float* __restrict__ K,
    const __hip_bfloat16* __restrict__ Wb,
    const float* __restrict__ SGN, float* __restrict__ OUT)
{
  const int t    = threadIdx.x;
  const int lane = t & 63;
  const int wv   = t >> 6;        // wave -> d-slice base wv*64
  const int brow = lane & 15;
  const int q    = lane >> 4;
  const int bh   = blockIdx.y;
  const int n0   = blockIdx.x * NCHUNK;

  // --- W fragments: rows m*Dc + wv*64 + dt*16 + brow, k = kh*32 + q*8
  short8 wf[4][4][2];
  {
    const __hip_bfloat16* wbase =
        Wb + ((size_t)bh * (Mc * Dc) + wv * 64 + brow) * Pc + q * 8;
    #pragma unroll
    for (int m = 0; m < 4; ++m) {
      #pragma unroll
      for (int dt = 0; dt < 4; ++dt) {
        const __hip_bfloat16* wp = wbase + (size_t)(m * Dc + dt * 16) * Pc;
        wf[m][dt][0] = *(const short8*)(wp);
        wf[m][dt][1] = *(const short8*)(wp + 32);
      }
    }
  }

  // --- signs in registers: sg[m][dt] covers d = wv*64 + dt*16 + q*4 .. +3
  f32x4 sg[4][4];
  #pragma unroll
  for (int m = 0; m < 4; ++m) {
    #pragma unroll
    for (int dt = 0; dt < 4; ++dt) {
      sg[m][dt] = *(const f32x4*)(SGN + m * Dc + wv * 64 + dt * 16 + q * 4);
    }
  }

  // X B-fragment source: lane holds X[n0+it*16+brow][k = kh*32 + q*8 + j]
  const float* xrow = ((n0 < Nc) ? (Q + ((size_t)bh * Nc + n0) * Pc)
                                 : (K + ((size_t)bh * Nc + (n0 - Nc)) * Pc))
                      + (size_t)brow * Pc + q * 8;
  float* obase = OUT + ((size_t)bh * NXc + n0 + brow) * Dc + wv * 64 + q * 4;

  // prologue: load tile 0
  f32x4 xa = *(const f32x4*)(xrow);
  f32x4 xb = *(const f32x4*)(xrow + 4);
  f32x4 xc = *(const f32x4*)(xrow + 32);
  f32x4 xd = *(const f32x4*)(xrow + 36);

  for (int it = 0; it < NT; ++it) {
    // convert current X tile fp32 -> bf16 B-frags
    short8 b0, b1;
    {
      union { short8 s; uint4 u; } c0, c1;
      c0.u.x = bfpack(xa.x, xa.y); c0.u.y = bfpack(xa.z, xa.w);
      c0.u.z = bfpack(xb.x, xb.y); c0.u.w = bfpack(xb.z, xb.w);
      c1.u.x = bfpack(xc.x, xc.y); c1.u.y = bfpack(xc.z, xc.w);
      c1.u.z = bfpack(xd.x, xd.y); c1.u.w = bfpack(xd.z, xd.w);
      b0 = c0.s; b1 = c1.s;
    }
    // prefetch next tile's X (register double-buffer; ~1 iter of latency slack)
    if (it + 1 < NT) {
      const float* xn = xrow + (size_t)(it + 1) * 16 * Pc;
      xa = *(const f32x4*)(xn);
      xb = *(const f32x4*)(xn + 4);
      xc = *(const f32x4*)(xn + 32);
      xd = *(const f32x4*)(xn + 36);
    }

    float* orow = obase + (size_t)it * 16 * Dc;
    #pragma unroll
    for (int dt = 0; dt < 4; ++dt) {
      f32x4 acc = {0.f, 0.f, 0.f, 0.f};
      #pragma unroll
      for (int m = 0; m < 4; ++m) {
        f32x4 c = {0.f, 0.f, 0.f, 0.f};
        c = __builtin_amdgcn_mfma_f32_16x16x32_bf16(wf[m][dt][0], b0, c, 0, 0, 0);
        c = __builtin_amdgcn_mfma_f32_16x16x32_bf16(wf[m][dt][1], b1, c, 0, 0, 0);
        const f32x4 s = sg[m][dt];
        acc.x = fmaf(s.x, fexp2(c.x), acc.x);
        acc.y = fmaf(s.y, fexp2(c.y), acc.y);
        acc.z = fmaf(s.z, fexp2(c.z), acc.z);
        acc.w = fmaf(s.w, fexp2(c.w), acc.w);
      }
      // n = n0+it*16+brow (col), d = wv*64 + dt*16 + q*4 + reg -> one f32x4
      *(f32x4*)(orow + dt * 16) = acc;
    }
  }
}

extern "C" void kernel_launch(void* const* d_in, const int* in_sizes, int n_in,
                              void* d_out, int out_size, void* d_ws, size_t ws_size,
                              hipStream_t stream) {
  (void)in_sizes; (void)n_in; (void)out_size; (void)ws_size;
  const float* Q   = (const float*)d_in[0];
  const float* K   = (const float*)d_in[1];
  const int*   SK  = (const int*)d_in[2];
  const float* SGN = (const float*)d_in[3];
  float* OUT = (float*)d_out;

  __hip_bfloat16* Wb = (__hip_bfloat16*)d_ws;  // 2 MiB

  prepass_kernel<<<dim3(512), dim3(256), 0, stream>>>(Q, K, SK, Wb);
  sketch_main<<<dim3(NXc / NCHUNK, BH), dim3(256), 0, stream>>>(Q, K, Wb, SGN, OUT);
}